// Round 1
// baseline (278.834 us; speedup 1.0000x reference)
//
#include <hip/hip_runtime.h>

#define AA (-0.75f)

__device__ __forceinline__ float k1f(float x) {
    // ((A+2)x - (A+3)) * x * x + 1
    return ((AA + 2.0f) * x - (AA + 3.0f)) * x * x + 1.0f;
}
__device__ __forceinline__ float k2f(float x) {
    // ((A x - 5A) x + 8A) x - 4A
    return ((AA * x - 5.0f * AA) * x + 8.0f * AA) * x - 4.0f * AA;
}

__device__ __forceinline__ int reflect_clip(int idx, int size) {
    int span = size - 1;
    int i = idx < 0 ? -idx : idx;
    i = i % (2 * span);          // i >= 0
    if (i > span) i = 2 * span - i;
    // already in [0, span]
    return i;
}

// One block per (b, h) output row. 256 threads.
// x-table (per-column 4 indices + 4 weights) built once in LDS,
// y indices/weights are block-uniform (scalar regs).
__global__ __launch_bounds__(256)
void pds_kernel(const float* __restrict__ x,
                const float* __restrict__ rate,
                const float* __restrict__ center,
                float* __restrict__ out)
{
    constexpr int C = 8, H = 512, W = 512;

    const int blk = blockIdx.x;      // b*H + h
    const int b = blk >> 9;
    const int h = blk & (H - 1);

    const float r  = rate[b];
    const float cx = center[2 * b + 0];
    const float cy = center[2 * b + 1];

    __shared__ int4   sxi[W];
    __shared__ float4 swx[W];

    // ---- y (uniform per block) ----
    const float gy = 0.00390625f * (float)h - 1.0f;      // 2/512 exact
    const float Gy = (gy - cy) / r + cy;
    const float iy = (Gy + 1.0f) * 0.5f * 511.0f;
    const float y0 = floorf(iy);
    const float ty = iy - y0;
    const int   y0i = (int)y0;
    const float wy0 = k2f(ty + 1.0f);
    const float wy1 = k1f(ty);
    const float wy2 = k1f(1.0f - ty);
    const float wy3 = k2f(2.0f - ty);
    const int yi0 = reflect_clip(y0i - 1, H);
    const int yi1 = reflect_clip(y0i    , H);
    const int yi2 = reflect_clip(y0i + 1, H);
    const int yi3 = reflect_clip(y0i + 2, H);

    // ---- x table into LDS ----
    for (int w = threadIdx.x; w < W; w += 256) {
        const float gx = 0.00390625f * (float)w - 1.0f;
        const float Gx = (gx - cx) / r + cx;
        const float ix = (Gx + 1.0f) * 0.5f * 511.0f;
        const float x0 = floorf(ix);
        const float t  = ix - x0;
        const int x0i  = (int)x0;
        swx[w] = make_float4(k2f(t + 1.0f), k1f(t), k1f(1.0f - t), k2f(2.0f - t));
        sxi[w] = make_int4(reflect_clip(x0i - 1, W),
                           reflect_clip(x0i    , W),
                           reflect_clip(x0i + 1, W),
                           reflect_clip(x0i + 2, W));
    }
    __syncthreads();

    const float* imgb = x + (size_t)b * C * H * W;

    for (int c = 0; c < C; ++c) {
        const float* img = imgb + (size_t)c * H * W;
        const float* r0 = img + (size_t)yi0 * W;
        const float* r1 = img + (size_t)yi1 * W;
        const float* r2 = img + (size_t)yi2 * W;
        const float* r3 = img + (size_t)yi3 * W;
        float* orow = out + (((size_t)b * C + c) * H + h) * W;

        for (int w = threadIdx.x; w < W; w += 256) {
            const int4   xi = sxi[w];
            const float4 wx = swx[w];
            const float s0 = wx.x * r0[xi.x] + wx.y * r0[xi.y] + wx.z * r0[xi.z] + wx.w * r0[xi.w];
            const float s1 = wx.x * r1[xi.x] + wx.y * r1[xi.y] + wx.z * r1[xi.z] + wx.w * r1[xi.w];
            const float s2 = wx.x * r2[xi.x] + wx.y * r2[xi.y] + wx.z * r2[xi.z] + wx.w * r2[xi.w];
            const float s3 = wx.x * r3[xi.x] + wx.y * r3[xi.y] + wx.z * r3[xi.z] + wx.w * r3[xi.w];
            orow[w] = wy0 * s0 + wy1 * s1 + wy2 * s2 + wy3 * s3;
        }
    }
}

extern "C" void kernel_launch(void* const* d_in, const int* in_sizes, int n_in,
                              void* d_out, int out_size, void* d_ws, size_t ws_size,
                              hipStream_t stream) {
    const float* x      = (const float*)d_in[0];
    const float* rate   = (const float*)d_in[1];
    const float* center = (const float*)d_in[2];
    float* out          = (float*)d_out;

    constexpr int B = 16, H = 512;
    dim3 grid(B * H);
    dim3 block(256);
    pds_kernel<<<grid, block, 0, stream>>>(x, rate, center, out);
}

// Round 2
// 60.539 us; speedup vs baseline: 4.6059x; 4.6059x over previous
//
#include <hip/hip_runtime.h>

#define AA (-0.75f)

__device__ __forceinline__ float k1f(float x) {
    // ((A+2)x - (A+3)) * x * x + 1
    return ((AA + 2.0f) * x - (AA + 3.0f)) * x * x + 1.0f;
}
__device__ __forceinline__ float k2f(float x) {
    // ((A x - 5A) x + 8A) x - 4A
    return ((AA * x - 5.0f * AA) * x + 8.0f * AA) * x - 4.0f * AA;
}

__device__ __forceinline__ int reflect_clip(int idx, int size) {
    int span = size - 1;
    int i = idx < 0 ? -idx : idx;
    i = i % (2 * span);
    if (i > span) i = 2 * span - i;
    return i;
}

// Separable bicubic: vertical filter (coalesced float4 global reads) -> LDS tmp,
// then horizontal 4-tap gather from LDS. One block per (b,h), 256 threads.
__global__ __launch_bounds__(256)
void pds2_kernel(const float* __restrict__ x,
                 const float* __restrict__ rate,
                 const float* __restrict__ center,
                 float* __restrict__ out)
{
    constexpr int C = 8, H = 512, W = 512;

    // XCD-chunked remap: 8192 blocks over 8 XCDs -> each XCD owns a
    // contiguous (b,h) range so h-neighbors (sharing input rows) hit the
    // same XCD L2. 8192 % 8 == 0 -> bijective.
    const int orig = blockIdx.x;
    const int id = (orig & 7) * 1024 + (orig >> 3);
    const int b = id >> 9;
    const int h = id & (H - 1);

    const float r  = rate[b];
    const float cx = center[2 * b + 0];
    const float cy = center[2 * b + 1];

    // ---- y taps (block-uniform) ----
    const float gy = 0.00390625f * (float)h - 1.0f;    // 2/512 exact
    const float Gy = (gy - cy) / r + cy;
    const float iy = (Gy + 1.0f) * 0.5f * 511.0f;
    const float y0 = floorf(iy);
    const float ty = iy - y0;
    const int   y0i = (int)y0;
    const float wy0 = k2f(ty + 1.0f);
    const float wy1 = k1f(ty);
    const float wy2 = k1f(1.0f - ty);
    const float wy3 = k2f(2.0f - ty);
    const size_t ro0 = (size_t)reflect_clip(y0i - 1, H) * W;
    const size_t ro1 = (size_t)reflect_clip(y0i    , H) * W;
    const size_t ro2 = (size_t)reflect_clip(y0i + 1, H) * W;
    const size_t ro3 = (size_t)reflect_clip(y0i + 2, H) * W;

    // ---- per-thread x taps for w0 = t and w1 = t + 256 ----
    const int t = threadIdx.x;
    int   xiA0, xiA1, xiA2, xiA3, xiB0, xiB1, xiB2, xiB3;
    float wxA0, wxA1, wxA2, wxA3, wxB0, wxB1, wxB2, wxB3;
    {
        const float gx = 0.00390625f * (float)t - 1.0f;
        const float Gx = (gx - cx) / r + cx;
        const float ix = (Gx + 1.0f) * 0.5f * 511.0f;
        const float x0 = floorf(ix);
        const float tx = ix - x0;
        const int x0i = (int)x0;
        wxA0 = k2f(tx + 1.0f); wxA1 = k1f(tx);
        wxA2 = k1f(1.0f - tx); wxA3 = k2f(2.0f - tx);
        xiA0 = reflect_clip(x0i - 1, W); xiA1 = reflect_clip(x0i, W);
        xiA2 = reflect_clip(x0i + 1, W); xiA3 = reflect_clip(x0i + 2, W);
    }
    {
        const int w = t + 256;
        const float gx = 0.00390625f * (float)w - 1.0f;
        const float Gx = (gx - cx) / r + cx;
        const float ix = (Gx + 1.0f) * 0.5f * 511.0f;
        const float x0 = floorf(ix);
        const float tx = ix - x0;
        const int x0i = (int)x0;
        wxB0 = k2f(tx + 1.0f); wxB1 = k1f(tx);
        wxB2 = k1f(1.0f - tx); wxB3 = k2f(2.0f - tx);
        xiB0 = reflect_clip(x0i - 1, W); xiB1 = reflect_clip(x0i, W);
        xiB2 = reflect_clip(x0i + 1, W); xiB3 = reflect_clip(x0i + 2, W);
    }

    __shared__ float tmp[C][W];   // 16 KiB: vertically-filtered rows, all channels

    // ---- vertical pass: coalesced float4 loads, combine in regs, write LDS ----
    const float* imgb = x + (size_t)b * C * H * W;
    #pragma unroll
    for (int k = 0; k < 4; ++k) {
        const int g  = t + k * 256;          // 1024 float4 groups: 8 c x 128
        const int c  = g >> 7;
        const int c4 = (g & 127) << 2;       // float index, 16B aligned
        const float* img = imgb + (size_t)c * (H * W);
        const float4 a0 = *(const float4*)(img + ro0 + c4);
        const float4 a1 = *(const float4*)(img + ro1 + c4);
        const float4 a2 = *(const float4*)(img + ro2 + c4);
        const float4 a3 = *(const float4*)(img + ro3 + c4);
        float4 v;
        v.x = wy0 * a0.x + wy1 * a1.x + wy2 * a2.x + wy3 * a3.x;
        v.y = wy0 * a0.y + wy1 * a1.y + wy2 * a2.y + wy3 * a3.y;
        v.z = wy0 * a0.z + wy1 * a1.z + wy2 * a2.z + wy3 * a3.z;
        v.w = wy0 * a0.w + wy1 * a1.w + wy2 * a2.w + wy3 * a3.w;
        *(float4*)&tmp[c][c4] = v;
    }
    __syncthreads();

    // ---- horizontal pass: 4 LDS taps per output, reuse taps across channels ----
    #pragma unroll
    for (int c = 0; c < C; ++c) {
        const float* tr = tmp[c];
        const float s0 = wxA0 * tr[xiA0] + wxA1 * tr[xiA1]
                       + wxA2 * tr[xiA2] + wxA3 * tr[xiA3];
        const float s1 = wxB0 * tr[xiB0] + wxB1 * tr[xiB1]
                       + wxB2 * tr[xiB2] + wxB3 * tr[xiB3];
        float* orow = out + (((size_t)b * C + c) * H + h) * W;
        orow[t]       = s0;
        orow[t + 256] = s1;
    }
}

extern "C" void kernel_launch(void* const* d_in, const int* in_sizes, int n_in,
                              void* d_out, int out_size, void* d_ws, size_t ws_size,
                              hipStream_t stream) {
    const float* x      = (const float*)d_in[0];
    const float* rate   = (const float*)d_in[1];
    const float* center = (const float*)d_in[2];
    float* out          = (float*)d_out;

    constexpr int B = 16, H = 512;
    dim3 grid(B * H);
    dim3 block(256);
    pds2_kernel<<<grid, block, 0, stream>>>(x, rate, center, out);
}